// Round 13
// baseline (290.212 us; speedup 1.0000x reference)
//
#include <hip/hip_runtime.h>
#include <hip/hip_bf16.h>
#include <math.h>

#define NPIX 4096

typedef __attribute__((ext_vector_type(8))) short s8;    // 8 x bf16 (4 VGPRs)
typedef __attribute__((ext_vector_type(4))) short s4;    // 4 x bf16 (2 VGPRs)
typedef __attribute__((ext_vector_type(16))) float f16v; // 16 x f32 (32x32 acc)

static __device__ __forceinline__ unsigned packbf2(float a, float b) {
    union { __hip_bfloat162 h; unsigned u; } x;
    x.h = __float22bfloat162_rn(make_float2(a, b));
    return x.u;
}
static __device__ __forceinline__ float2 unpackbf2(unsigned u) {
    float lo = __uint_as_float(u << 16);
    float hi = __uint_as_float(u & 0xffff0000u);
    return make_float2(lo, hi);
}
static __device__ __forceinline__ float fexp2(float x) {
#if __has_builtin(__builtin_amdgcn_exp2f)
    return __builtin_amdgcn_exp2f(x);   // raw v_exp_f32, no libm denormal fixup
#else
    return exp2f(x);
#endif
}

// ---------------------------------------------------------------------------
// Kernel 1: prep — q,k projections (bf16) + bf16 copy of x. (R4/R10 shape)
// ---------------------------------------------------------------------------
__global__ __launch_bounds__(256) void prep_kernel(
    const float* __restrict__ x,
    const float* __restrict__ Wq, const float* __restrict__ bq,
    const float* __restrict__ Wk, const float* __restrict__ bk,
    __hip_bfloat16* __restrict__ qbf, __hip_bfloat16* __restrict__ kbf,
    __hip_bfloat16* __restrict__ xbf)
{
    __shared__ float Xp[64][65];
    int t = threadIdx.x;
    int lane = t & 63;
    int grp  = t >> 6;               // 0..3, wave-uniform
    int b  = blockIdx.x >> 6;
    int n0 = (blockIdx.x & 63) << 6;

    const float* xb = x + ((size_t)b << 18);
    __hip_bfloat16* xbb = xbf + ((size_t)b << 18);
#pragma unroll
    for (int u = 0; u < 16; ++u) {
        int c = grp + u * 4;
        float v = xb[((size_t)c << 12) + n0 + lane];
        Xp[c][lane] = v;
        xbb[((size_t)c << 12) + n0 + lane] = __float2bfloat16(v);
    }
    __syncthreads();

    int o0 = grp * 2, o1 = o0 + 1;
    float qa0 = bq[o0], qa1 = bq[o1], ka0 = bk[o0], ka1 = bk[o1];
    const float* wq0 = Wq + o0 * 64; const float* wq1 = Wq + o1 * 64;
    const float* wk0 = Wk + o0 * 64; const float* wk1 = Wk + o1 * 64;
#pragma unroll
    for (int c = 0; c < 64; ++c) {
        float xv = Xp[c][lane];
        qa0 = fmaf(wq0[c], xv, qa0);
        qa1 = fmaf(wq1[c], xv, qa1);
        ka0 = fmaf(wk0[c], xv, ka0);
        ka1 = fmaf(wk1[c], xv, ka1);
    }
    qa0 *= 1.4426950408889634f;        // fold log2(e): flash uses exp2
    qa1 *= 1.4426950408889634f;
    int pix = b * NPIX + n0 + lane;
    *(__hip_bfloat162*)(qbf + (size_t)pix * 8 + o0) =
        __float22bfloat162_rn(make_float2(qa0, qa1));
    *(__hip_bfloat162*)(kbf + (size_t)pix * 8 + o0) =
        __float22bfloat162_rn(make_float2(ka0, ka1));
}

// ---------------------------------------------------------------------------
// Kernel 2: flash partial + INLINE MERGE (R13). Structure = R12 register-P
// (verified): 1024 blocks x 512 thr; wave w: i-group g=w>>2, j-stripe sw=w&3.
// After storing its partial, each block tickets counters[rest]; the LAST of
// the 4 sId blocks for a (b,i) group re-reads the 4 partials (L2-hot) and
// does the Wv projection + bias + gamma + residual inline — merge kernel
// and its launch gap deleted. Device-scope fences around the ticket.
// ---------------------------------------------------------------------------
__global__ __launch_bounds__(512, 4) void flash_part_kernel(
    const __hip_bfloat16* __restrict__ qbf, const __hip_bfloat16* __restrict__ kbf,
    const __hip_bfloat16* __restrict__ xbf,
    __hip_bfloat16* __restrict__ Opart, float* __restrict__ Lp,
    const float* __restrict__ Wv, const float* __restrict__ bv,
    const float* __restrict__ x, const float* __restrict__ gamma,
    float* __restrict__ out, int* __restrict__ counters)
{
    // phase A: Xs double buffer [2][64][140] shorts = 2*17920 B
    // phase B: Osh [2 g][32 i][68] f32 @0 (17408B) | Lsh [8][32] @34816 (1024B)
    // phase C (merge): OshM [64][68] @0 | WvsM @17408 | LinvM @33792 | bvsM @34048
    __shared__ __align__(16) char pool[35840];
    __shared__ int ticket;

    int t = threadIdx.x;
    int w    = t >> 6;               // 0..7
    int lane = t & 63;
    int l32  = lane & 31;
    int lh   = lane >> 5;
    int g    = w >> 2;               // i-group (32 i)
    int sw   = w & 3;                // j-stripe (32 j)

    int blk  = blockIdx.x;
    int sId  = blk >> 8;
    int rest = blk & 255;
    int b    = rest >> 6;
    int i0   = (rest & 63) << 6;
    int jbase = sId << 10;

    const s8 zero8 = {0, 0, 0, 0, 0, 0, 0, 0};

    // Q B-frag (score): B[k=lh*8+r -> d][n=l32 -> i]; lh=1 half zeroed (d<8)
    s8 qf;
    {
        s8 qv = *(const s8*)(qbf + ((size_t)(b * NPIX + i0 + g * 32 + l32) << 3));
        qf = (lh == 0) ? qv : zero8;
    }

    f16v acc[2];                      // acc[cm]: O[c=cm*32+row(r,lh)][i=l32]
    f16v zero16;
#pragma unroll
    for (int r = 0; r < 16; ++r) { acc[0][r] = 0.f; acc[1][r] = 0.f; zero16[r] = 0.f; }
    float lsum = 0.f;

    const __hip_bfloat16* kb = kbf + ((size_t)(b * NPIX) << 3);
    const unsigned short* xg = (const unsigned short*)xbf + ((size_t)b << 18);

    // staging: thread t writes 32 B: row c = t>>3, seg = t&7 (16 shorts)
    int c = t >> 3, seg = t & 7;
    const unsigned short* xsrc = xg + ((size_t)c << 12) + seg * 16;
    int xdst = c * 140 + seg * 16;    // shorts

    // preload tile 0
    uint2 sv0, sv1, sv2, sv3;
    s8 kf;
    {
        const unsigned short* p = xsrc + jbase;
        sv0 = *(const uint2*)(p);     sv1 = *(const uint2*)(p + 4);
        sv2 = *(const uint2*)(p + 8); sv3 = *(const uint2*)(p + 12);
        kf = *(const s8*)(kb + ((size_t)(jbase + sw * 32 + l32) << 3));
    }

    int bufp = 0;
    for (int tile = 0; tile < 8; ++tile) {
        unsigned short* Xb = (unsigned short*)(pool + bufp * 17920);

        // stage-write from prefetched regs
        *(uint2*)(Xb + xdst + 0)  = sv0;
        *(uint2*)(Xb + xdst + 4)  = sv1;
        *(uint2*)(Xb + xdst + 8)  = sv2;
        *(uint2*)(Xb + xdst + 12) = sv3;

        // score (no Xs dependency): S^T[j=row(r,lh)][i=l32] for own stripe
        f16v sC = __builtin_amdgcn_mfma_f32_32x32x16_bf16(kf, qf, zero16, 0, 0, 0);
        float e[16];
#pragma unroll
        for (int r = 0; r < 16; ++r) e[r] = fexp2(sC[r]);
#pragma unroll
        for (int r = 0; r < 16; ++r) lsum += e[r];
        unsigned P2[8];
#pragma unroll
        for (int s = 0; s < 8; ++s) P2[s] = packbf2(e[2 * s], e[2 * s + 1]);

        // prefetch next tile (wraps; in flight under P·x)
        {
            int jn = jbase + (((tile + 1) & 7) << 7);
            const unsigned short* p = xsrc + jn;
            sv0 = *(const uint2*)(p);     sv1 = *(const uint2*)(p + 4);
            sv2 = *(const uint2*)(p + 8); sv3 = *(const uint2*)(p + 12);
            kf = *(const s8*)(kb + ((size_t)(jn + sw * 32 + l32) << 3));
        }

        __syncthreads();   // Xs[bufp] ready (double buffer -> only barrier)

        // P·x: O[c][i] += X[c][j-stripe] · P[j][i]
#if __has_builtin(__builtin_amdgcn_mfma_f32_32x32x8bf16_1k)
#pragma unroll
        for (int cm = 0; cm < 2; ++cm) {
            const unsigned short* xrow = Xb + (cm * 32 + l32) * 140 + sw * 32 + lh * 4;
#pragma unroll
            for (int q = 0; q < 4; ++q) {
                s4 xf = *(const s4*)(xrow + q * 8);
                union { uint2 u; s4 v; } pu;
                pu.u.x = P2[2 * q]; pu.u.y = P2[2 * q + 1];
                acc[cm] = __builtin_amdgcn_mfma_f32_32x32x8bf16_1k(xf, pu.v, acc[cm], 0, 0, 0);
            }
        }
#else
        {
            unsigned X0 = __shfl_xor(P2[0], 32), X1 = __shfl_xor(P2[1], 32);
            unsigned X2 = __shfl_xor(P2[2], 32), X3 = __shfl_xor(P2[3], 32);
            unsigned X4 = __shfl_xor(P2[4], 32), X5 = __shfl_xor(P2[5], 32);
            unsigned X6 = __shfl_xor(P2[6], 32), X7 = __shfl_xor(P2[7], 32);
            union { uint4 u[2]; s8 v[2]; } bf;
            bf.u[0].x = lh ? X2 : P2[0]; bf.u[0].y = lh ? X3 : P2[1];
            bf.u[0].z = lh ? P2[2] : X0; bf.u[0].w = lh ? P2[3] : X1;
            bf.u[1].x = lh ? X6 : P2[4]; bf.u[1].y = lh ? X7 : P2[5];
            bf.u[1].z = lh ? P2[6] : X4; bf.u[1].w = lh ? P2[7] : X5;
#pragma unroll
            for (int cm = 0; cm < 2; ++cm) {
                const unsigned short* xrow = Xb + (cm * 32 + l32) * 140 + sw * 32 + lh * 8;
#pragma unroll
                for (int q = 0; q < 2; ++q) {
                    union { uint2 u[2]; s8 v; } xu;
                    xu.u[0] = *(const uint2*)(xrow + q * 16);
                    xu.u[1] = *(const uint2*)(xrow + q * 16 + 4);
                    acc[cm] = __builtin_amdgcn_mfma_f32_32x32x16_bf16(xu.v, bf.v[q], acc[cm], 0, 0, 0);
                }
            }
        }
#endif
        bufp ^= 1;
    }

    // ---------------- epilogue: store partial ----------------
    float* Osh = (float*)pool;                    // [2 g][32 i][68]
    float* Lsh = (float*)(pool + 35840 - 1024);   // [8 w][32]

    lsum += __shfl_xor(lsum, 32);                 // full 32-j stripe sum per i

    __syncthreads();   // all waves done with Xs buffers
    if (lh == 0) Lsh[w * 32 + l32] = lsum;

    float* OshG = Osh + g * 2176;
    for (int s = 0; s < 4; ++s) {
        __syncthreads();
        if (sw == s) {
#pragma unroll
            for (int cm = 0; cm < 2; ++cm)
#pragma unroll
                for (int r = 0; r < 16; ++r) {
                    int cc = cm * 32 + (r & 3) + 8 * (r >> 2) + 4 * lh;
                    float* p = OshG + l32 * 68 + cc;
                    if (s == 0) *p = acc[cm][r];
                    else        *p += acc[cm][r];
                }
        }
    }
    __syncthreads();

    if (t < 64) {
        int gi = t, gg = gi >> 5, ii = gi & 31;
        Lp[(size_t)blk * 64 + gi] =
            Lsh[(gg * 4 + 0) * 32 + ii] + Lsh[(gg * 4 + 1) * 32 + ii] +
            Lsh[(gg * 4 + 2) * 32 + ii] + Lsh[(gg * 4 + 3) * 32 + ii];
    }

    // store partial O bf16: thread t -> row i = t>>3, cols [(t&7)*8, +8)
    {
        int i = t >> 3, c0 = (t & 7) << 3;
        const float* src = Osh + (i >> 5) * 2176 + (i & 31) * 68 + c0;
        uint4 pk;
        pk.x = packbf2(src[0], src[1]); pk.y = packbf2(src[2], src[3]);
        pk.z = packbf2(src[4], src[5]); pk.w = packbf2(src[6], src[7]);
        *(uint4*)(Opart + (size_t)blk * 4096 + i * 64 + c0) = pk;
    }

    // ---------------- inline merge: last sId block of this (b,i) group ------
    __threadfence();                  // release: Opart/Lp visible device-wide
    if (t == 0) ticket = atomicAdd(&counters[rest], 1);
    __syncthreads();                  // also: all pool reads above complete
    if (ticket != 3) return;
    __threadfence();                  // acquire: see the other 3 partials

    float* OshM  = (float*)pool;                 // [64 i][68]
    float* WvsM  = (float*)(pool + 17408);       // [64][64]
    float* LinvM = (float*)(pool + 33792);       // [64]
    float* bvsM  = (float*)(pool + 34048);       // [64]

    if (t < 64) {
        float lt = Lp[(size_t)(0 * 256 + rest) * 64 + t]
                 + Lp[(size_t)(1 * 256 + rest) * 64 + t]
                 + Lp[(size_t)(2 * 256 + rest) * 64 + t]
                 + Lp[(size_t)(3 * 256 + rest) * 64 + t];
        LinvM[t] = 1.0f / lt;
        bvsM[t] = bv[t];
    }
    {
        const float4* wsrc = (const float4*)Wv;
        float4* wdst = (float4*)WvsM;
        wdst[t] = wsrc[t];
        wdst[t + 512] = wsrc[t + 512];
    }
    __syncthreads();

    // combine partials: thread t -> row i = t>>3 (0..63), cols [(t&7)*8, +8)
    {
        int i = t >> 3, c0 = (t & 7) << 3;
        float o[8];
#pragma unroll
        for (int k = 0; k < 8; ++k) o[k] = 0.f;
#pragma unroll
        for (int s2 = 0; s2 < 4; ++s2) {
            size_t base = (size_t)(s2 * 256 + rest) * 4096 + i * 64 + c0;
            uint4 pk = *(const uint4*)(Opart + base);
            float2 e0 = unpackbf2(pk.x), e1 = unpackbf2(pk.y);
            float2 e2 = unpackbf2(pk.z), e3 = unpackbf2(pk.w);
            o[0] += e0.x; o[1] += e0.y; o[2] += e1.x; o[3] += e1.y;
            o[4] += e2.x; o[5] += e2.y; o[6] += e3.x; o[7] += e3.y;
        }
        float* dst = OshM + i * 68 + c0;
        *(float4*)(dst + 0) = make_float4(o[0], o[1], o[2], o[3]);
        *(float4*)(dst + 4) = make_float4(o[4], o[5], o[6], o[7]);
    }
    __syncthreads();

    // projection: i = t&63 (pixel), cg = t>>6 -> 8 output channels each
    {
        int i  = t & 63;
        int cg = t >> 6;
        float inv = LinvM[i];
        float res[8];
#pragma unroll
        for (int k = 0; k < 8; ++k) res[k] = 0.f;
#pragma unroll 4
        for (int cb = 0; cb < 16; ++cb) {
            float4 o = *(const float4*)(OshM + i * 68 + cb * 4);
#pragma unroll
            for (int k = 0; k < 8; ++k) {
                float4 wv4 = *(const float4*)(WvsM + (cg * 8 + k) * 64 + cb * 4);
                res[k] = fmaf(wv4.x, o.x, fmaf(wv4.y, o.y, fmaf(wv4.z, o.z, fmaf(wv4.w, o.w, res[k]))));
            }
        }
        float gam = gamma[0];
        const float* xr = x + ((size_t)b << 18) + i0;
        float* outp = out + ((size_t)b << 18) + i0;
#pragma unroll
        for (int k = 0; k < 8; ++k) {
            int cch = cg * 8 + k;
            float attn = fmaf(res[k], inv, bvsM[cch]);
            size_t off = ((size_t)cch << 12) + i;
            outp[off] = fmaf(gam, attn, xr[off]);
        }
    }
}

extern "C" void kernel_launch(void* const* d_in, const int* in_sizes, int n_in,
                              void* d_out, int out_size, void* d_ws, size_t ws_size,
                              hipStream_t stream) {
    const float* x     = (const float*)d_in[0];
    const float* Wq    = (const float*)d_in[1];
    const float* bq    = (const float*)d_in[2];
    const float* Wk    = (const float*)d_in[3];
    const float* bk    = (const float*)d_in[4];
    const float* Wv    = (const float*)d_in[5];
    const float* bv    = (const float*)d_in[6];
    const float* gamma = (const float*)d_in[7];
    float* out = (float*)d_out;

    // ws: qbf 256KB | kbf 256KB | xbf 2MB | Opart 8MB | Lp 256KB | counters 1KB
    __hip_bfloat16* qbf   = (__hip_bfloat16*)d_ws;
    __hip_bfloat16* kbf   = qbf + (size_t)4 * NPIX * 8;
    __hip_bfloat16* xbf   = kbf + (size_t)4 * NPIX * 8;
    __hip_bfloat16* Opart = xbf + (size_t)4 * NPIX * 64;
    float* Lp = (float*)(Opart + (size_t)1024 * 4096);
    int* counters = (int*)(Lp + 1024 * 64);

    hipMemsetAsync(counters, 0, 256 * sizeof(int), stream);
    prep_kernel<<<256, 256, 0, stream>>>(x, Wq, bq, Wk, bk, qbf, kbf, xbf);
    flash_part_kernel<<<1024, 512, 0, stream>>>(qbf, kbf, xbf, Opart, Lp,
                                                Wv, bv, x, gamma, out, counters);
}

// Round 14
// 108.042 us; speedup vs baseline: 2.6861x; 2.6861x over previous
//
#include <hip/hip_runtime.h>
#include <hip/hip_bf16.h>
#include <math.h>

#define NPIX 4096

typedef __attribute__((ext_vector_type(8))) short s8;    // 8 x bf16 (4 VGPRs)
typedef __attribute__((ext_vector_type(4))) short s4;    // 4 x bf16 (2 VGPRs)
typedef __attribute__((ext_vector_type(16))) float f16v; // 16 x f32 (32x32 acc)

static __device__ __forceinline__ unsigned packbf2(float a, float b) {
    union { __hip_bfloat162 h; unsigned u; } x;
    x.h = __float22bfloat162_rn(make_float2(a, b));
    return x.u;
}
static __device__ __forceinline__ float fexp2(float x) {
#if __has_builtin(__builtin_amdgcn_exp2f)
    return __builtin_amdgcn_exp2f(x);
#else
    return exp2f(x);
#endif
}

// ---------------------------------------------------------------------------
// Kernel 1: prep — q,k projections (bf16) + bf16 copy of x. (R4/R10 shape)
// ---------------------------------------------------------------------------
__global__ __launch_bounds__(256) void prep_kernel(
    const float* __restrict__ x,
    const float* __restrict__ Wq, const float* __restrict__ bq,
    const float* __restrict__ Wk, const float* __restrict__ bk,
    __hip_bfloat16* __restrict__ qbf, __hip_bfloat16* __restrict__ kbf,
    __hip_bfloat16* __restrict__ xbf)
{
    __shared__ float Xp[64][65];
    int t = threadIdx.x;
    int lane = t & 63;
    int grp  = t >> 6;               // 0..3, wave-uniform
    int b  = blockIdx.x >> 6;
    int n0 = (blockIdx.x & 63) << 6;

    const float* xb = x + ((size_t)b << 18);
    __hip_bfloat16* xbb = xbf + ((size_t)b << 18);
#pragma unroll
    for (int u = 0; u < 16; ++u) {
        int c = grp + u * 4;
        float v = xb[((size_t)c << 12) + n0 + lane];
        Xp[c][lane] = v;
        xbb[((size_t)c << 12) + n0 + lane] = __float2bfloat16(v);
    }
    __syncthreads();

    int o0 = grp * 2, o1 = o0 + 1;
    float qa0 = bq[o0], qa1 = bq[o1], ka0 = bk[o0], ka1 = bk[o1];
    const float* wq0 = Wq + o0 * 64; const float* wq1 = Wq + o1 * 64;
    const float* wk0 = Wk + o0 * 64; const float* wk1 = Wk + o1 * 64;
#pragma unroll
    for (int c = 0; c < 64; ++c) {
        float xv = Xp[c][lane];
        qa0 = fmaf(wq0[c], xv, qa0);
        qa1 = fmaf(wq1[c], xv, qa1);
        ka0 = fmaf(wk0[c], xv, ka0);
        ka1 = fmaf(wk1[c], xv, ka1);
    }
    qa0 *= 1.4426950408889634f;        // fold log2(e): flash uses exp2
    qa1 *= 1.4426950408889634f;
    int pix = b * NPIX + n0 + lane;
    *(__hip_bfloat162*)(qbf + (size_t)pix * 8 + o0) =
        __float22bfloat162_rn(make_float2(qa0, qa1));
    *(__hip_bfloat162*)(kbf + (size_t)pix * 8 + o0) =
        __float22bfloat162_rn(make_float2(ka0, ka1));
}

// ---------------------------------------------------------------------------
// Kernel 2: fused flash (R14). NO cross-block combine, NO fences (R13 lesson:
// device-scope fences serialize via L2 writeback on non-coherent XCDs).
// Grid 512 = (b, 32-i tile) x 512 thr: 8 waves = 8 j-stripes (32 j each) of a
// 256-j tile; 16 tiles cover all 4096 j. 2 blocks/CU -> 4 waves/SIMD.
// Per tile: stage X[64][256] into LDS (single buffer, 2 barriers/tile);
// score mfma_32x32x16 (kf,qf) -> exp2 -> packed-pair P2 feeds 32x32x8 MFMAs
// directly (register-P, verified R12). acc = O[64c x 32i] per wave.
// Epilogue: 2-tree stripe reduction + l-sum + Wv projection + residual, all
// block-local.
// ---------------------------------------------------------------------------
__global__ __launch_bounds__(512, 4) void flash_fused_kernel(
    const __hip_bfloat16* __restrict__ qbf, const __hip_bfloat16* __restrict__ kbf,
    const __hip_bfloat16* __restrict__ xbf,
    const float* __restrict__ Wv, const float* __restrict__ bv,
    const float* __restrict__ x, const float* __restrict__ gamma,
    float* __restrict__ out)
{
    // main loop: Xs [64][260] shorts @0 = 33280 B (stride 260 -> 2-bank-stride
    //            A-frag reads = free 2-way; 520 B rows keep 8B alignment)
    // epilogue:  OshA [32][68] @0 | OshB @8704 | Linv @17408 | bvs @17536 |
    //            Wvs @17792 (16384) | Lsh [8][32] @34176 (beyond Xs: no overlap)
    __shared__ __align__(16) char pool[35200];
    unsigned short* Xs = (unsigned short*)pool;

    int t = threadIdx.x;
    int w    = t >> 6;               // 0..7 = j-stripe
    int lane = t & 63;
    int l32  = lane & 31;
    int lh   = lane >> 5;

    int b  = blockIdx.x >> 7;
    int i0 = (blockIdx.x & 127) << 5;

    const s8 zero8 = {0, 0, 0, 0, 0, 0, 0, 0};

    // Q B-frag: B[k=lh*8+r -> d][n=l32 -> i=i0+l32]; lh=1 half zeroed (d<8)
    s8 qf;
    {
        s8 qv = *(const s8*)(qbf + ((size_t)(b * NPIX + i0 + l32) << 3));
        qf = (lh == 0) ? qv : zero8;
    }

    f16v acc[2];                      // acc[cm]: O[c=cm*32+row(r,lh)][i=l32]
    f16v zero16;
#pragma unroll
    for (int r = 0; r < 16; ++r) { acc[0][r] = 0.f; acc[1][r] = 0.f; zero16[r] = 0.f; }
    float lsum = 0.f;

    const __hip_bfloat16* kb = kbf + ((size_t)(b * NPIX) << 3);
    const unsigned short* xg = (const unsigned short*)xbf + ((size_t)b << 18);

    // staging: thread t -> row c = t>>3, seg = t&7 (32 shorts = 64 B each)
    int c = t >> 3, seg = t & 7;
    const unsigned short* xsrc = xg + ((size_t)c << 12) + seg * 32;
    int xdst = c * 260 + seg * 32;    // shorts

    // preload tile 0
    uint2 pv[8];
    s8 kf;
    {
        const unsigned short* p = xsrc;
#pragma unroll
        for (int u = 0; u < 8; ++u) pv[u] = *(const uint2*)(p + u * 4);
        kf = *(const s8*)(kb + ((size_t)(w * 32 + l32) << 3));
    }

    for (int jt = 0; jt < 16; ++jt) {
        __syncthreads();   // A: previous tile's P·x readers done with Xs

        // stage-write from prefetched regs (8 x uint2, 8B-aligned)
        {
            unsigned short* dstp = Xs + xdst;
#pragma unroll
            for (int u = 0; u < 8; ++u) *(uint2*)(dstp + u * 4) = pv[u];
        }

        // score (no Xs dependency): S^T[j=stripe row][i=l32]
        f16v sC = __builtin_amdgcn_mfma_f32_32x32x16_bf16(kf, qf, zero16, 0, 0, 0);
        float e[16];
#pragma unroll
        for (int r = 0; r < 16; ++r) e[r] = fexp2(sC[r]);
#pragma unroll
        for (int r = 0; r < 16; ++r) lsum += e[r];
        unsigned P2[8];
#pragma unroll
        for (int s = 0; s < 8; ++s) P2[s] = packbf2(e[2 * s], e[2 * s + 1]);

        __syncthreads();   // B: Xs ready (lgkm-only drain for this write set)

        // prefetch next tile (wraps; in flight under P·x)
        {
            int jn = ((jt + 1) & 15) << 8;
            const unsigned short* p = xsrc + jn;
#pragma unroll
            for (int u = 0; u < 8; ++u) pv[u] = *(const uint2*)(p + u * 4);
            kf = *(const s8*)(kb + ((size_t)(jn + w * 32 + l32) << 3));
        }

        // P·x: O[c][i] += X[c][j-stripe] · P[j][i]
#if __has_builtin(__builtin_amdgcn_mfma_f32_32x32x8bf16_1k)
#pragma unroll
        for (int cm = 0; cm < 2; ++cm) {
            const unsigned short* xrow = Xs + (cm * 32 + l32) * 260 + w * 32 + lh * 4;
#pragma unroll
            for (int q = 0; q < 4; ++q) {
                s4 xf = *(const s4*)(xrow + q * 8);
                union { uint2 u; s4 v; } pu;
                pu.u.x = P2[2 * q]; pu.u.y = P2[2 * q + 1];
                acc[cm] = __builtin_amdgcn_mfma_f32_32x32x8bf16_1k(xf, pu.v, acc[cm], 0, 0, 0);
            }
        }
#else
        {
            unsigned X0 = __shfl_xor(P2[0], 32), X1 = __shfl_xor(P2[1], 32);
            unsigned X2 = __shfl_xor(P2[2], 32), X3 = __shfl_xor(P2[3], 32);
            unsigned X4 = __shfl_xor(P2[4], 32), X5 = __shfl_xor(P2[5], 32);
            unsigned X6 = __shfl_xor(P2[6], 32), X7 = __shfl_xor(P2[7], 32);
            union { uint4 u[2]; s8 v[2]; } bf;
            bf.u[0].x = lh ? X2 : P2[0]; bf.u[0].y = lh ? X3 : P2[1];
            bf.u[0].z = lh ? P2[2] : X0; bf.u[0].w = lh ? P2[3] : X1;
            bf.u[1].x = lh ? X6 : P2[4]; bf.u[1].y = lh ? X7 : P2[5];
            bf.u[1].z = lh ? P2[6] : X4; bf.u[1].w = lh ? P2[7] : X5;
#pragma unroll
            for (int cm = 0; cm < 2; ++cm) {
                const unsigned short* xrow = Xs + (cm * 32 + l32) * 260 + w * 32 + lh * 8;
#pragma unroll
                for (int q = 0; q < 2; ++q) {
                    union { uint2 u[2]; s8 v; } xu;
                    xu.u[0] = *(const uint2*)(xrow + q * 16);
                    xu.u[1] = *(const uint2*)(xrow + q * 16 + 4);
                    acc[cm] = __builtin_amdgcn_mfma_f32_32x32x16_bf16(xu.v, bf.v[q], acc[cm], 0, 0, 0);
                }
            }
        }
#endif
    }

    // ---------------- epilogue (block-local, no fences) ----------------
    float* OshA = (float*)pool;                  // [32 i][68]
    float* OshB = (float*)(pool + 8704);         // [32 i][68]
    float* Linv = (float*)(pool + 17408);        // [32]
    float* bvs  = (float*)(pool + 17536);        // [64]
    float* Wvs  = (float*)(pool + 17792);        // [64][64]
    float* Lsh  = (float*)(pool + 34176);        // [8][32] (no Xs overlap)

    lsum += __shfl_xor(lsum, 32);                // full 32-j stripe sum per i
    if (lh == 0) Lsh[w * 32 + l32] = lsum;       // region disjoint from Xs

    // 2-tree stripe reduction: waves 0-3 -> OshA, waves 4-7 -> OshB
    float* Og = (w >> 2) ? OshB : OshA;
    for (int s = 0; s < 4; ++s) {
        __syncthreads();
        if ((w & 3) == s) {
#pragma unroll
            for (int cm = 0; cm < 2; ++cm)
#pragma unroll
                for (int r = 0; r < 16; ++r) {
                    int cc = cm * 32 + (r & 3) + 8 * (r >> 2) + 4 * lh;
                    float* p = Og + l32 * 68 + cc;
                    if (s == 0) *p = acc[cm][r];
                    else        *p += acc[cm][r];
                }
        }
    }
    __syncthreads();

    // stage Linv / bv / Wv (Wvs region beyond OshB, before Lsh)
    if (t < 32) {
        float lt = 0.f;
#pragma unroll
        for (int ww = 0; ww < 8; ++ww) lt += Lsh[ww * 32 + t];
        Linv[t] = 1.0f / lt;
    }
    if (t < 64) bvs[t] = bv[t];
    {
        const float4* wsrc = (const float4*)Wv;
        float4* wdst = (float4*)Wvs;
        wdst[t] = wsrc[t];
        wdst[t + 512] = wsrc[t + 512];
    }
    __syncthreads();

    // projection + residual: i = t&31, cg = t>>5 (0..15) -> 4 channels each
    {
        int i  = t & 31;
        int cg = t >> 5;
        float inv = Linv[i];
        float res[4] = {0.f, 0.f, 0.f, 0.f};
#pragma unroll 4
        for (int cb = 0; cb < 16; ++cb) {
            float4 oa = *(const float4*)(OshA + i * 68 + cb * 4);
            float4 ob = *(const float4*)(OshB + i * 68 + cb * 4);
            float4 o = make_float4(oa.x + ob.x, oa.y + ob.y, oa.z + ob.z, oa.w + ob.w);
#pragma unroll
            for (int k = 0; k < 4; ++k) {
                const float4 wv4 = *(const float4*)(Wvs + (cg * 4 + k) * 64 + cb * 4);
                res[k] = fmaf(wv4.x, o.x, fmaf(wv4.y, o.y, fmaf(wv4.z, o.z, fmaf(wv4.w, o.w, res[k]))));
            }
        }
        float g = gamma[0];
        const float* xr = x + ((size_t)b << 18) + i0;
        float* outp = out + ((size_t)b << 18) + i0;
#pragma unroll
        for (int k = 0; k < 4; ++k) {
            int cch = cg * 4 + k;
            float attn = fmaf(res[k], inv, bvs[cch]);
            size_t off = ((size_t)cch << 12) + i;
            outp[off] = fmaf(g, attn, xr[off]);
        }
    }
}

extern "C" void kernel_launch(void* const* d_in, const int* in_sizes, int n_in,
                              void* d_out, int out_size, void* d_ws, size_t ws_size,
                              hipStream_t stream) {
    const float* x     = (const float*)d_in[0];
    const float* Wq    = (const float*)d_in[1];
    const float* bq    = (const float*)d_in[2];
    const float* Wk    = (const float*)d_in[3];
    const float* bk    = (const float*)d_in[4];
    const float* Wv    = (const float*)d_in[5];
    const float* bv    = (const float*)d_in[6];
    const float* gamma = (const float*)d_in[7];
    float* out = (float*)d_out;

    // ws: qbf 256KB | kbf 256KB | xbf 2MB
    __hip_bfloat16* qbf = (__hip_bfloat16*)d_ws;
    __hip_bfloat16* kbf = qbf + (size_t)4 * NPIX * 8;
    __hip_bfloat16* xbf = kbf + (size_t)4 * NPIX * 8;

    prep_kernel<<<256, 256, 0, stream>>>(x, Wq, bq, Wk, bk, qbf, kbf, xbf);
    flash_fused_kernel<<<512, 512, 0, stream>>>(qbf, kbf, xbf, Wv, bv, x, gamma, out);
}